// Round 5
// baseline (984.731 us; speedup 1.0000x reference)
//
#include <hip/hip_runtime.h>
#include <cstdint>

#define NP 4096   // points
#define DIMF 2048 // feature dim
#define NC 256    // classes
#define MAXIT 100
#define NBLK 256  // cooperative grid size

typedef __bf16 bf16x8 __attribute__((ext_vector_type(8)));
typedef float f32x4 __attribute__((ext_vector_type(4)));

__device__ inline unsigned short f2b(float f) {
  union { float f; unsigned u; } v; v.f = f;
  unsigned r = v.u + 0x7fffu + ((v.u >> 16) & 1u);  // RNE
  return (unsigned short)(r >> 16);
}
__device__ inline float b2f(unsigned short u) {
  union { unsigned u; float f; } v; v.u = ((unsigned)u) << 16;
  return v.f;
}

// ---- contention-free grid barrier: per-block flags (128B stride) + gen word ----
// block b!=0: release-store flags[b]=phase; spin-acquire on gen >= phase.
// block 0: threads 1..nblk-1 spin-acquire on flags[tid]; then release-store gen.
// Release/acquire at AGENT scope gives cross-XCD visibility (same machinery as cg).
__device__ __forceinline__ void gridbar(unsigned* flags, unsigned* gen,
                                        unsigned phase, int tid) {
  __syncthreads();
  if (blockIdx.x == 0) {
    if (tid >= 1 && tid < NBLK) {
      while (__hip_atomic_load(&flags[tid * 32], __ATOMIC_ACQUIRE,
                               __HIP_MEMORY_SCOPE_AGENT) < phase)
        __builtin_amdgcn_s_sleep(1);
    }
    __syncthreads();
    if (tid == 0)
      __hip_atomic_store(gen, phase, __ATOMIC_RELEASE, __HIP_MEMORY_SCOPE_AGENT);
  } else {
    if (tid == 0) {
      __hip_atomic_store(&flags[blockIdx.x * 32], phase, __ATOMIC_RELEASE,
                         __HIP_MEMORY_SCOPE_AGENT);
      while (__hip_atomic_load(gen, __ATOMIC_ACQUIRE,
                               __HIP_MEMORY_SCOPE_AGENT) < phase)
        __builtin_amdgcn_s_sleep(1);
    }
  }
  __syncthreads();
}

// ---------------- init (ws poisoned 0xAA before every call) ----------------
__global__ __launch_bounds__(256) void initk(double* Ed, float* sig,
                                             unsigned* flags, unsigned* gen) {
  int t = threadIdx.x;
  if (t < MAXIT) Ed[t] = 0.0;
  if (t == 0) { *sig = 0.0f; *gen = 0u; }
  for (int i = t; i < NBLK * 32; i += 256) flags[i] = 0u;
}

// ---------------- W f32 -> bf16 ----------------
__global__ __launch_bounds__(256) void castk(const float* __restrict__ W,
                                             unsigned short* __restrict__ Wb) {
  size_t i = ((size_t)blockIdx.x * 256 + threadIdx.x) * 4;
  float4 v = *(const float4*)&W[i];
  ushort4 o; o.x = f2b(v.x); o.y = f2b(v.y); o.z = f2b(v.z); o.w = f2b(v.w);
  *(ushort4*)&Wb[i] = o;
}

// ---------------- row-normalize x -> F(bf16), x -> xb(bf16), sqF ----------------
__global__ __launch_bounds__(256) void rownorm(const float* __restrict__ x,
                                               unsigned short* __restrict__ F,
                                               unsigned short* __restrict__ xb,
                                               float* __restrict__ sqF) {
  const int row = blockIdx.x, tid = threadIdx.x;
  const float* rp = x + (size_t)row * DIMF;
  float4 a = *(const float4*)&rp[tid * 8];
  float4 b = *(const float4*)&rp[tid * 8 + 4];
  float f[8] = {a.x, a.y, a.z, a.w, b.x, b.y, b.z, b.w};
  float s = 0.f;
#pragma unroll
  for (int k = 0; k < 8; k++) s += f[k] * f[k];
  __shared__ float red[256];
  red[tid] = s; __syncthreads();
  for (int st = 128; st >= 1; st >>= 1) {
    if (tid < st) red[tid] += red[tid + st];
    __syncthreads();
  }
  float inv = 1.0f / sqrtf(red[0]);
  __syncthreads();
  unsigned short fb[8], xbv[8];
  float s2 = 0.f;
#pragma unroll
  for (int k = 0; k < 8; k++) {
    fb[k] = f2b(f[k] * inv);
    xbv[k] = f2b(f[k]);
    float q = b2f(fb[k]);
    s2 += q * q;
  }
  *(ushort4*)&F[(size_t)row * DIMF + tid * 8]      = *(ushort4*)&fb[0];
  *(ushort4*)&F[(size_t)row * DIMF + tid * 8 + 4]  = *(ushort4*)&fb[4];
  *(ushort4*)&xb[(size_t)row * DIMF + tid * 8]     = *(ushort4*)&xbv[0];
  *(ushort4*)&xb[(size_t)row * DIMF + tid * 8 + 4] = *(ushort4*)&xbv[4];
  red[tid] = s2; __syncthreads();
  for (int st = 128; st >= 1; st >>= 1) {
    if (tid < st) red[tid] += red[tid + st];
    __syncthreads();
  }
  if (tid == 0) sqF[row] = red[0];
}

// ---------------- reg-staged GEMM (BK=64): C = A[M,K]*B[N,K]^T ----
// EPI 0: C = acc + aux[col]   (logits, aux = bias)
// EPI 1: C = max(aux[row]+aux[col]-2*acc, 0)   (d2, aux = sqF)
template <int BM, int BN, int WR, int WC, int EPI>
__global__ __launch_bounds__(256) void gemm_bt(const unsigned short* __restrict__ A,
                                               const unsigned short* __restrict__ B,
                                               float* __restrict__ C,
                                               int M, int N, int K,
                                               const float* __restrict__ aux) {
  constexpr int WM = BM / WR, WN = BN / WC;
  constexpr int TM = WM / 16, TN = WN / 16;
  constexpr int LDT = 72;  // padded row stride (bf16): 144B -> 2-way-free b128 reads
  __shared__ __align__(16) unsigned short sA[BM * LDT];
  __shared__ __align__(16) unsigned short sB[BN * LDT];
  const int tid = threadIdx.x;
  const int wid = tid >> 6, lane = tid & 63;
  const int wr = wid / WC, wc = wid % WC;
  const int l15 = lane & 15, l16 = lane >> 4;
  const int bm = blockIdx.x * BM, bn = blockIdx.y * BN;
  f32x4 acc[TM][TN];
#pragma unroll
  for (int m = 0; m < TM; m++)
#pragma unroll
    for (int n = 0; n < TN; n++) acc[m][n] = 0.0f;

  for (int k0 = 0; k0 < K; k0 += 64) {
    for (int i = tid; i < BM * 8; i += 256) {
      int r = i >> 3, ch = i & 7;
      *(uint4*)&sA[r * LDT + ch * 8] =
          *(const uint4*)&A[(size_t)(bm + r) * K + k0 + ch * 8];
    }
    for (int i = tid; i < BN * 8; i += 256) {
      int r = i >> 3, ch = i & 7;
      *(uint4*)&sB[r * LDT + ch * 8] =
          *(const uint4*)&B[(size_t)(bn + r) * K + k0 + ch * 8];
    }
    __syncthreads();
#pragma unroll
    for (int kk = 0; kk < 2; ++kk) {
      bf16x8 af[TM], bf[TN];
#pragma unroll
      for (int m = 0; m < TM; m++)
        af[m] = *(const bf16x8*)&sA[(wr * WM + m * 16 + l15) * LDT + kk * 32 + l16 * 8];
#pragma unroll
      for (int n = 0; n < TN; n++)
        bf[n] = *(const bf16x8*)&sB[(wc * WN + n * 16 + l15) * LDT + kk * 32 + l16 * 8];
#pragma unroll
      for (int m = 0; m < TM; m++)
#pragma unroll
        for (int n = 0; n < TN; n++)
          acc[m][n] = __builtin_amdgcn_mfma_f32_16x16x32_bf16(af[m], bf[n], acc[m][n], 0, 0, 0);
    }
    __syncthreads();
  }
#pragma unroll
  for (int m = 0; m < TM; m++) {
    int row0 = bm + wr * WM + m * 16 + l16 * 4;
#pragma unroll
    for (int n = 0; n < TN; n++) {
      int col = bn + wc * WN + n * 16 + l15;
#pragma unroll
      for (int j = 0; j < 4; j++) {
        int row = row0 + j;
        float v = acc[m][n][j];
        if (EPI == 0) {
          C[(size_t)row * NC + col] = v + aux[col];
        } else {
          float d = aux[row] + aux[col] - 2.0f * v;
          C[(size_t)row * NP + col] = fmaxf(d, 0.0f);
        }
      }
    }
  }
}

// ---------------- unary = -log(softmax(logits)+1e-10), one wave per row ----------
__global__ __launch_bounds__(256) void unary_k(const float* __restrict__ logits,
                                               float* __restrict__ unary) {
  const int wid = threadIdx.x >> 6, lane = threadIdx.x & 63;
  const int row = blockIdx.x * 4 + wid;
  const float* lp = logits + (size_t)row * NC;
  float v[4];
#pragma unroll
  for (int j = 0; j < 4; j++) v[j] = lp[lane + 64 * j];
  float m = fmaxf(fmaxf(v[0], v[1]), fmaxf(v[2], v[3]));
#pragma unroll
  for (int o = 32; o >= 1; o >>= 1) m = fmaxf(m, __shfl_xor(m, o, 64));
  float e[4], s = 0.f;
#pragma unroll
  for (int j = 0; j < 4; j++) { e[j] = expf(v[j] - m); s += e[j]; }
#pragma unroll
  for (int o = 32; o >= 1; o >>= 1) s += __shfl_xor(s, o, 64);
  float* up = unary + (size_t)row * NC;
#pragma unroll
  for (int j = 0; j < 4; j++) up[lane + 64 * j] = -logf(e[j] / s + 1e-10f);
}

// ---------------- Y0 = softmax(-unary) -> out(f32), Yt(bf16 transposed) ----------
__global__ __launch_bounds__(256) void smax0(const float* __restrict__ unary,
                                             float* __restrict__ Yout,
                                             unsigned short* __restrict__ Yt) {
  const int tid = threadIdx.x;
  const int wid = tid >> 6, lane = tid & 63;
  const int rb = blockIdx.x;  // 16 rows per block
  __shared__ __align__(16) unsigned short yt[256][24];
  for (int rr = wid; rr < 16; rr += 4) {
    const int row = rb * 16 + rr;
    float z[4];
#pragma unroll
    for (int j = 0; j < 4; j++) z[j] = -unary[(size_t)row * NC + lane + 64 * j];
    float m = fmaxf(fmaxf(z[0], z[1]), fmaxf(z[2], z[3]));
#pragma unroll
    for (int o = 32; o >= 1; o >>= 1) m = fmaxf(m, __shfl_xor(m, o, 64));
    float e[4], s = 0.f;
#pragma unroll
    for (int j = 0; j < 4; j++) { e[j] = expf(z[j] - m); s += e[j]; }
#pragma unroll
    for (int o = 32; o >= 1; o >>= 1) s += __shfl_xor(s, o, 64);
#pragma unroll
    for (int j = 0; j < 4; j++) {
      int c = lane + 64 * j;
      float y = e[j] / s;
      Yout[(size_t)row * NC + c] = y;
      yt[c][rr] = f2b(y);
    }
  }
  __syncthreads();
  int c = tid;
  uint4 a = *(const uint4*)&yt[c][0];
  uint4 bq = *(const uint4*)&yt[c][8];
  unsigned short* dst = Yt + (size_t)c * NP + rb * 16;
  *(uint4*)dst = a;
  *(uint4*)(dst + 8) = bq;
}

// ---------------- per-row 5th-smallest d2 -> atomicAdd(sqrt) into sig ------------
__global__ __launch_bounds__(256) void kth_k(const float* __restrict__ d2,
                                             float* __restrict__ sig) {
  const int row = blockIdx.x, tid = threadIdx.x;
  const float* rp = d2 + (size_t)row * NP;
  float b[5];
#pragma unroll
  for (int q = 0; q < 5; q++) b[q] = __int_as_float(0x7f800000);
  for (int s = 0; s < 16; s++) {
    float v = rp[tid + 256 * s];
    if (v < b[4]) {
      b[4] = v;
#pragma unroll
      for (int q = 4; q > 0; q--)
        if (b[q] < b[q - 1]) { float t = b[q]; b[q] = b[q - 1]; b[q - 1] = t; }
    }
  }
  __shared__ float ls[256 * 5];
#pragma unroll
  for (int q = 0; q < 5; q++) ls[tid * 5 + q] = b[q];
  __syncthreads();
  for (int st = 128; st >= 1; st >>= 1) {
    if (tid < st) {
      float* xs = &ls[tid * 5];
      float* ys = &ls[(tid + st) * 5];
      float r[5]; int i = 0, j = 0;
#pragma unroll
      for (int q = 0; q < 5; q++) r[q] = (xs[i] <= ys[j]) ? xs[i++] : ys[j++];
#pragma unroll
      for (int q = 0; q < 5; q++) xs[q] = r[q];
    }
    __syncthreads();
  }
  if (tid == 0) atomicAdd(sig, sqrtf(ls[4]));
}

// ---------------- Kb = bf16(exp(-d2/(2 sigma^2))) --------------------------------
__global__ __launch_bounds__(256) void expk(const float* __restrict__ d2,
                                            unsigned short* __restrict__ Kb,
                                            const float* __restrict__ sig) {
  float sigma = (*sig) * (1.0f / NP);
  float c = -1.0f / (2.0f * sigma * sigma);
  size_t i = ((size_t)blockIdx.x * 256 + threadIdx.x) * 4;
  float4 v = *(const float4*)&d2[i];
  ushort4 o;
  o.x = f2b(expf(v.x * c)); o.y = f2b(expf(v.y * c));
  o.z = f2b(expf(v.z * c)); o.w = f2b(expf(v.w * c));
  *(ushort4*)&Kb[i] = o;
}

// ---------------- persistent cooperative loop kernel -----------------------------
// 256 blocks x 512 threads (8 waves).  block = (rb, ks): rb in [0,64) rows 64,
// ks in [0,4) k-slice of 1024.  Per iter:
//   phase A: partial[ks] = Kb[rb-rows][kslice] @ Yt[:, kslice]^T  (reg-staged LDS)
//   gridbar
//   phase B: rows blk*16..+15: P = sum_s partial; softmax(P - unary);
//            out(f32), Yt(bf16 transposed), E -> atomicAdd Ed[iter]
//   gridbar; uniform convergence check -> break.
__global__ __launch_bounds__(512, 4) void loop_k(const unsigned short* __restrict__ Kb,
                                                 unsigned short* __restrict__ Yt,
                                                 const float* __restrict__ unary,
                                                 float* __restrict__ out,
                                                 float* __restrict__ partial,
                                                 double* __restrict__ Ed,
                                                 unsigned* __restrict__ flags,
                                                 unsigned* __restrict__ gen) {
  const int tid = threadIdx.x, lane = tid & 63, wid = tid >> 6;
  const int blk = blockIdx.x;
  const int rb = blk >> 2, ks = blk & 3;   // 64-row block, 1024-wide k-slice
  const int wr = wid >> 2, wc = wid & 3;   // 2x4 wave grid, wave tile 32x64
  const int l15 = lane & 15, l16 = lane >> 4;
  constexpr int LDT = 72;                  // padded (144B row stride: 2-way-free)
  __shared__ __align__(16) unsigned short sA[64 * LDT];    //  9.2 KB
  __shared__ __align__(16) unsigned short sB[256 * LDT];   // 36.9 KB
  __shared__ __align__(16) unsigned short yt[256 * 24];    // 12.3 KB
  __shared__ double ered[8];
  float oldEf = __int_as_float(0x7f800000);

  for (int iter = 0; iter < MAXIT; ++iter) {
    // ---------------- phase A: partial GEMM (reg-staged) ----
    f32x4 acc[2][4];
#pragma unroll
    for (int m = 0; m < 2; m++)
#pragma unroll
      for (int n = 0; n < 4; n++) acc[m][n] = 0.0f;

    for (int kb = 0; kb < 16; ++kb) {
      const int kofs = ks * 1024 + kb * 64;
      {
        int u = tid, r = u >> 3, c = u & 7;
        *(uint4*)&sA[r * LDT + c * 8] =
            *(const uint4*)&Kb[(size_t)(rb * 64 + r) * NP + kofs + c * 8];
      }
#pragma unroll
      for (int j = 0; j < 4; ++j) {
        int u = j * 512 + tid, r = u >> 3, c = u & 7;
        *(uint4*)&sB[r * LDT + c * 8] =
            *(const uint4*)&Yt[(size_t)r * NP + kofs + c * 8];
      }
      __syncthreads();
#pragma unroll
      for (int kk = 0; kk < 2; ++kk) {
        bf16x8 af[2], bf[4];
#pragma unroll
        for (int m = 0; m < 2; ++m)
          af[m] = *(const bf16x8*)&sA[(wr * 32 + m * 16 + l15) * LDT + (kk * 4 + l16) * 8];
#pragma unroll
        for (int n = 0; n < 4; ++n)
          bf[n] = *(const bf16x8*)&sB[(wc * 64 + n * 16 + l15) * LDT + (kk * 4 + l16) * 8];
#pragma unroll
        for (int m = 0; m < 2; ++m)
#pragma unroll
          for (int n = 0; n < 4; ++n)
            acc[m][n] = __builtin_amdgcn_mfma_f32_16x16x32_bf16(af[m], bf[n], acc[m][n], 0, 0, 0);
      }
      __syncthreads();
    }
    {
      float* pp = partial + (size_t)ks * ((size_t)NP * NC);
#pragma unroll
      for (int m = 0; m < 2; ++m) {
        int row0 = rb * 64 + wr * 32 + m * 16 + l16 * 4;
#pragma unroll
        for (int n = 0; n < 4; ++n) {
          int col = wc * 64 + n * 16 + l15;
#pragma unroll
          for (int j = 0; j < 4; ++j)
            pp[(size_t)(row0 + j) * NC + col] = acc[m][n][j];
        }
      }
    }
    gridbar(flags, gen, 2u * iter + 1u, tid);

    // ---------------- phase B: reduce + softmax + E (16 rows per block) ----------
    double ep = 0.0;
#pragma unroll
    for (int h = 0; h < 2; ++h) {
      const int rr = wid * 2 + h;
      const int row = blk * 16 + rr;
      const int c0 = lane * 4;
      float pv[4] = {0.f, 0.f, 0.f, 0.f};
#pragma unroll
      for (int s = 0; s < 4; ++s) {
        float4 t4 = *(const float4*)&partial[(size_t)s * ((size_t)NP * NC) +
                                             (size_t)row * NC + c0];
        pv[0] += t4.x; pv[1] += t4.y; pv[2] += t4.z; pv[3] += t4.w;
      }
      float4 u4 = *(const float4*)&unary[(size_t)row * NC + c0];
      float uu[4] = {u4.x, u4.y, u4.z, u4.w};
      float z[4];
#pragma unroll
      for (int q = 0; q < 4; ++q) z[q] = pv[q] - uu[q];
      float m = fmaxf(fmaxf(z[0], z[1]), fmaxf(z[2], z[3]));
#pragma unroll
      for (int o = 32; o >= 1; o >>= 1) m = fmaxf(m, __shfl_xor(m, o, 64));
      float e[4], ssum = 0.f;
#pragma unroll
      for (int q = 0; q < 4; ++q) { e[q] = expf(z[q] - m); ssum += e[q]; }
#pragma unroll
      for (int o = 32; o >= 1; o >>= 1) ssum += __shfl_xor(ssum, o, 64);
      float inv = 1.0f / ssum;
      float4 o4;
      float y[4];
#pragma unroll
      for (int q = 0; q < 4; ++q) {
        y[q] = e[q] * inv;
        ep += (double)(y[q] * (uu[q] - pv[q] + logf(fmaxf(y[q], 1e-20f))));
        yt[(c0 + q) * 24 + rr] = f2b(y[q]);
      }
      o4.x = y[0]; o4.y = y[1]; o4.z = y[2]; o4.w = y[3];
      *(float4*)&out[(size_t)row * NC + c0] = o4;
    }
#pragma unroll
    for (int o = 32; o >= 1; o >>= 1) ep += __shfl_xor(ep, o, 64);
    if (lane == 0) ered[wid] = ep;
    __syncthreads();
    if (tid < 256) {  // pack 16 transposed rows for class c=tid
      uint4 a = *(const uint4*)&yt[tid * 24];
      uint4 bq = *(const uint4*)&yt[tid * 24 + 8];
      unsigned short* dst = Yt + (size_t)tid * NP + (size_t)blk * 16;
      *(uint4*)dst = a;
      *(uint4*)(dst + 8) = bq;
    }
    if (tid == 0) {
      double eblk = 0.0;
#pragma unroll
      for (int w = 0; w < 8; ++w) eblk += ered[w];
      atomicAdd(&Ed[iter], eblk);
    }
    gridbar(flags, gen, 2u * iter + 2u, tid);

    double Ec = __hip_atomic_load(&Ed[iter], __ATOMIC_RELAXED, __HIP_MEMORY_SCOPE_AGENT);
    float Ef = (float)Ec;
    if (iter > 1 && fabsf(Ef - oldEf) <= 1e-8f * fabsf(oldEf)) break;  // frozen
    oldEf = Ef;
  }
}

extern "C" void kernel_launch(void* const* d_in, const int* in_sizes, int n_in,
                              void* d_out, int out_size, void* d_ws, size_t ws_size,
                              hipStream_t stream) {
  const float* x = (const float*)d_in[0];
  const float* W = (const float*)d_in[1];
  const float* bias = (const float*)d_in[2];
  float* out = (float*)d_out;

  char* p = (char*)d_ws;
  auto take = [&](size_t bytes) {
    char* r = p;
    p += (bytes + 255) & ~(size_t)255;
    return r;
  };
  float* d2          = (float*)take((size_t)NP * NP * 4);          // 64 MB (reused as partials)
  unsigned short* Kb = (unsigned short*)take((size_t)NP * NP * 2); // 32 MB
  unsigned short* F  = (unsigned short*)take((size_t)NP * DIMF * 2);
  unsigned short* xb = (unsigned short*)take((size_t)NP * DIMF * 2);
  unsigned short* Wb = (unsigned short*)take((size_t)NC * DIMF * 2);
  unsigned short* Yt = (unsigned short*)take((size_t)NC * NP * 2);
  float* logits = (float*)take((size_t)NP * NC * 4);
  float* unary  = (float*)take((size_t)NP * NC * 4);
  float* sqF    = (float*)take((size_t)NP * 4);
  float* sig    = (float*)take(256);
  double* Ed    = (double*)take(MAXIT * 8);
  unsigned* flags = (unsigned*)take((size_t)NBLK * 32 * 4);  // 128B-strided flags
  unsigned* gen   = (unsigned*)take(256);
  float* partial = d2;  // d2 dead after expk; 16 MB of partials fit in its 64 MB

  initk<<<1, 256, 0, stream>>>(Ed, sig, flags, gen);
  castk<<<512, 256, 0, stream>>>(W, Wb);
  rownorm<<<NP, 256, 0, stream>>>(x, F, xb, sqF);
  // logits = x @ W^T + b
  gemm_bt<64, 64, 4, 1, 0><<<dim3(64, 4), 256, 0, stream>>>(xb, Wb, logits, NP, NC, DIMF, bias);
  unary_k<<<1024, 256, 0, stream>>>(logits, unary);
  smax0<<<256, 256, 0, stream>>>(unary, out, Yt);
  // d2 = max(sq_i + sq_j - 2 F F^T, 0)
  gemm_bt<128, 128, 2, 2, 1><<<dim3(32, 32), 256, 0, stream>>>(F, F, d2, NP, NP, DIMF, sqF);
  kth_k<<<NP, 256, 0, stream>>>(d2, sig);
  expk<<<16384, 256, 0, stream>>>(d2, Kb, sig);
  // whole laplacian-optimization loop in one persistent cooperative kernel
  {
    const unsigned short* Kb_a = Kb;
    unsigned short* Yt_a = Yt;
    const float* un_a = unary;
    float* out_a = out;
    float* pa_a = partial;
    double* Ed_a = Ed;
    unsigned* fl_a = flags;
    unsigned* ge_a = gen;
    void* args[] = {(void*)&Kb_a, (void*)&Yt_a, (void*)&un_a, (void*)&out_a,
                    (void*)&pa_a, (void*)&Ed_a, (void*)&fl_a, (void*)&ge_a};
    hipLaunchCooperativeKernel((const void*)loop_k, dim3(NBLK), dim3(512),
                               args, 0, stream);
  }
}

// Round 6
// 782.453 us; speedup vs baseline: 1.2585x; 1.2585x over previous
//
#include <hip/hip_runtime.h>
#include <cstdint>

#define NP 4096   // points
#define DIMF 2048 // feature dim
#define NC 256    // classes
#define MAXIT 100
#define NBLK2 128 // loop kernel grid size

typedef __bf16 bf16x8 __attribute__((ext_vector_type(8)));
typedef float f32x4 __attribute__((ext_vector_type(4)));

__device__ inline unsigned short f2b(float f) {
  union { float f; unsigned u; } v; v.f = f;
  unsigned r = v.u + 0x7fffu + ((v.u >> 16) & 1u);  // RNE
  return (unsigned short)(r >> 16);
}
__device__ inline float b2f(unsigned short u) {
  union { unsigned u; float f; } v; v.u = ((unsigned)u) << 16;
  return v.f;
}

// ---- contention-free grid barrier (homemade; blocks must be co-resident) ----
__device__ __forceinline__ void gridbar(unsigned* flags, unsigned* gen,
                                        unsigned phase, int tid, int nblk) {
  __syncthreads();
  if (blockIdx.x == 0) {
    if (tid >= 1 && tid < nblk) {
      while (__hip_atomic_load(&flags[tid * 32], __ATOMIC_ACQUIRE,
                               __HIP_MEMORY_SCOPE_AGENT) < phase)
        __builtin_amdgcn_s_sleep(1);
    }
    __syncthreads();
    if (tid == 0)
      __hip_atomic_store(gen, phase, __ATOMIC_RELEASE, __HIP_MEMORY_SCOPE_AGENT);
  } else {
    if (tid == 0) {
      __hip_atomic_store(&flags[blockIdx.x * 32], phase, __ATOMIC_RELEASE,
                         __HIP_MEMORY_SCOPE_AGENT);
      while (__hip_atomic_load(gen, __ATOMIC_ACQUIRE,
                               __HIP_MEMORY_SCOPE_AGENT) < phase)
        __builtin_amdgcn_s_sleep(1);
    }
  }
  __syncthreads();
}

// ---------------- init (ws poisoned 0xAA before every call) ----------------
__global__ __launch_bounds__(256) void initk(double* Ed, float* sig,
                                             unsigned* flags, unsigned* gen) {
  int t = threadIdx.x;
  if (t < MAXIT) Ed[t] = 0.0;
  if (t == 0) { *sig = 0.0f; *gen = 0u; }
  for (int i = t; i < 256 * 32; i += 256) flags[i] = 0u;
}

// ---------------- W f32 -> bf16 ----------------
__global__ __launch_bounds__(256) void castk(const float* __restrict__ W,
                                             unsigned short* __restrict__ Wb) {
  size_t i = ((size_t)blockIdx.x * 256 + threadIdx.x) * 4;
  float4 v = *(const float4*)&W[i];
  ushort4 o; o.x = f2b(v.x); o.y = f2b(v.y); o.z = f2b(v.z); o.w = f2b(v.w);
  *(ushort4*)&Wb[i] = o;
}

// ---------------- row-normalize x -> F(bf16), x -> xb(bf16), sqF ----------------
__global__ __launch_bounds__(256) void rownorm(const float* __restrict__ x,
                                               unsigned short* __restrict__ F,
                                               unsigned short* __restrict__ xb,
                                               float* __restrict__ sqF) {
  const int row = blockIdx.x, tid = threadIdx.x;
  const float* rp = x + (size_t)row * DIMF;
  float4 a = *(const float4*)&rp[tid * 8];
  float4 b = *(const float4*)&rp[tid * 8 + 4];
  float f[8] = {a.x, a.y, a.z, a.w, b.x, b.y, b.z, b.w};
  float s = 0.f;
#pragma unroll
  for (int k = 0; k < 8; k++) s += f[k] * f[k];
  __shared__ float red[256];
  red[tid] = s; __syncthreads();
  for (int st = 128; st >= 1; st >>= 1) {
    if (tid < st) red[tid] += red[tid + st];
    __syncthreads();
  }
  float inv = 1.0f / sqrtf(red[0]);
  __syncthreads();
  unsigned short fb[8], xbv[8];
  float s2 = 0.f;
#pragma unroll
  for (int k = 0; k < 8; k++) {
    fb[k] = f2b(f[k] * inv);
    xbv[k] = f2b(f[k]);
    float q = b2f(fb[k]);
    s2 += q * q;
  }
  *(ushort4*)&F[(size_t)row * DIMF + tid * 8]      = *(ushort4*)&fb[0];
  *(ushort4*)&F[(size_t)row * DIMF + tid * 8 + 4]  = *(ushort4*)&fb[4];
  *(ushort4*)&xb[(size_t)row * DIMF + tid * 8]     = *(ushort4*)&xbv[0];
  *(ushort4*)&xb[(size_t)row * DIMF + tid * 8 + 4] = *(ushort4*)&xbv[4];
  red[tid] = s2; __syncthreads();
  for (int st = 128; st >= 1; st >>= 1) {
    if (tid < st) red[tid] += red[tid + st];
    __syncthreads();
  }
  if (tid == 0) sqF[row] = red[0];
}

// ---------------- r1-validated reg-staged GEMM (BK=32): C = A[M,K]*B[N,K]^T ----
// EPI 0: C = acc + aux[col]   (logits, aux = bias)
// EPI 1: C = max(aux[row]+aux[col]-2*acc, 0)   (d2, aux = sqF)
template <int BM, int BN, int WR, int WC, int EPI>
__global__ __launch_bounds__(256) void gemm_bt(const unsigned short* __restrict__ A,
                                               const unsigned short* __restrict__ B,
                                               float* __restrict__ C,
                                               int M, int N, int K,
                                               const float* __restrict__ aux) {
  constexpr int WM = BM / WR, WN = BN / WC;
  constexpr int TM = WM / 16, TN = WN / 16;
  constexpr int LDT = 40;
  __shared__ __align__(16) unsigned short sA[BM * LDT];
  __shared__ __align__(16) unsigned short sB[BN * LDT];
  const int tid = threadIdx.x;
  const int wid = tid >> 6, lane = tid & 63;
  const int wr = wid / WC, wc = wid % WC;
  const int l15 = lane & 15, l16 = lane >> 4;
  const int bm = blockIdx.x * BM, bn = blockIdx.y * BN;
  f32x4 acc[TM][TN];
#pragma unroll
  for (int m = 0; m < TM; m++)
#pragma unroll
    for (int n = 0; n < TN; n++) acc[m][n] = 0.0f;

  for (int k0 = 0; k0 < K; k0 += 32) {
    for (int i = tid; i < BM * 4; i += 256) {
      int r = i >> 2, ch = i & 3;
      *(uint4*)&sA[r * LDT + ch * 8] =
          *(const uint4*)&A[(size_t)(bm + r) * K + k0 + ch * 8];
    }
    for (int i = tid; i < BN * 4; i += 256) {
      int r = i >> 2, ch = i & 3;
      *(uint4*)&sB[r * LDT + ch * 8] =
          *(const uint4*)&B[(size_t)(bn + r) * K + k0 + ch * 8];
    }
    __syncthreads();
    bf16x8 af[TM], bf[TN];
#pragma unroll
    for (int m = 0; m < TM; m++)
      af[m] = *(const bf16x8*)&sA[(wr * WM + m * 16 + l15) * LDT + l16 * 8];
#pragma unroll
    for (int n = 0; n < TN; n++)
      bf[n] = *(const bf16x8*)&sB[(wc * WN + n * 16 + l15) * LDT + l16 * 8];
#pragma unroll
    for (int m = 0; m < TM; m++)
#pragma unroll
      for (int n = 0; n < TN; n++)
        acc[m][n] = __builtin_amdgcn_mfma_f32_16x16x32_bf16(af[m], bf[n], acc[m][n], 0, 0, 0);
    __syncthreads();
  }
#pragma unroll
  for (int m = 0; m < TM; m++) {
    int row0 = bm + wr * WM + m * 16 + l16 * 4;
#pragma unroll
    for (int n = 0; n < TN; n++) {
      int col = bn + wc * WN + n * 16 + l15;
#pragma unroll
      for (int j = 0; j < 4; j++) {
        int row = row0 + j;
        float v = acc[m][n][j];
        if (EPI == 0) {
          C[(size_t)row * NC + col] = v + aux[col];
        } else {
          float d = aux[row] + aux[col] - 2.0f * v;
          C[(size_t)row * NP + col] = fmaxf(d, 0.0f);
        }
      }
    }
  }
}

// ---------------- unary = -log(softmax(logits)+1e-10), one wave per row ----------
__global__ __launch_bounds__(256) void unary_k(const float* __restrict__ logits,
                                               float* __restrict__ unary) {
  const int wid = threadIdx.x >> 6, lane = threadIdx.x & 63;
  const int row = blockIdx.x * 4 + wid;
  const float* lp = logits + (size_t)row * NC;
  float v[4];
#pragma unroll
  for (int j = 0; j < 4; j++) v[j] = lp[lane + 64 * j];
  float m = fmaxf(fmaxf(v[0], v[1]), fmaxf(v[2], v[3]));
#pragma unroll
  for (int o = 32; o >= 1; o >>= 1) m = fmaxf(m, __shfl_xor(m, o, 64));
  float e[4], s = 0.f;
#pragma unroll
  for (int j = 0; j < 4; j++) { e[j] = expf(v[j] - m); s += e[j]; }
#pragma unroll
  for (int o = 32; o >= 1; o >>= 1) s += __shfl_xor(s, o, 64);
  float* up = unary + (size_t)row * NC;
#pragma unroll
  for (int j = 0; j < 4; j++) up[lane + 64 * j] = -logf(e[j] / s + 1e-10f);
}

// ---------------- Y0 = softmax(-unary) -> out(f32), Yt0(bf16 transposed) ----------
__global__ __launch_bounds__(256) void smax0(const float* __restrict__ unary,
                                             float* __restrict__ Yout,
                                             unsigned short* __restrict__ Yt) {
  const int tid = threadIdx.x;
  const int wid = tid >> 6, lane = tid & 63;
  const int rb = blockIdx.x;  // 16 rows per block
  __shared__ __align__(16) unsigned short yt[256][24];
  for (int rr = wid; rr < 16; rr += 4) {
    const int row = rb * 16 + rr;
    float z[4];
#pragma unroll
    for (int j = 0; j < 4; j++) z[j] = -unary[(size_t)row * NC + lane + 64 * j];
    float m = fmaxf(fmaxf(z[0], z[1]), fmaxf(z[2], z[3]));
#pragma unroll
    for (int o = 32; o >= 1; o >>= 1) m = fmaxf(m, __shfl_xor(m, o, 64));
    float e[4], s = 0.f;
#pragma unroll
    for (int j = 0; j < 4; j++) { e[j] = expf(z[j] - m); s += e[j]; }
#pragma unroll
    for (int o = 32; o >= 1; o >>= 1) s += __shfl_xor(s, o, 64);
#pragma unroll
    for (int j = 0; j < 4; j++) {
      int c = lane + 64 * j;
      float y = e[j] / s;
      Yout[(size_t)row * NC + c] = y;
      yt[c][rr] = f2b(y);
    }
  }
  __syncthreads();
  int c = tid;
  uint4 a = *(const uint4*)&yt[c][0];
  uint4 bq = *(const uint4*)&yt[c][8];
  unsigned short* dst = Yt + (size_t)c * NP + rb * 16;
  *(uint4*)dst = a;
  *(uint4*)(dst + 8) = bq;
}

// ---------------- per-row 5th-smallest d2 -> atomicAdd(sqrt) into sig ------------
__global__ __launch_bounds__(256) void kth_k(const float* __restrict__ d2,
                                             float* __restrict__ sig) {
  const int row = blockIdx.x, tid = threadIdx.x;
  const float* rp = d2 + (size_t)row * NP;
  float b[5];
#pragma unroll
  for (int q = 0; q < 5; q++) b[q] = __int_as_float(0x7f800000);
  for (int s = 0; s < 16; s++) {
    float v = rp[tid + 256 * s];
    if (v < b[4]) {
      b[4] = v;
#pragma unroll
      for (int q = 4; q > 0; q--)
        if (b[q] < b[q - 1]) { float t = b[q]; b[q] = b[q - 1]; b[q - 1] = t; }
    }
  }
  __shared__ float ls[256 * 5];
#pragma unroll
  for (int q = 0; q < 5; q++) ls[tid * 5 + q] = b[q];
  __syncthreads();
  for (int st = 128; st >= 1; st >>= 1) {
    if (tid < st) {
      float* xs = &ls[tid * 5];
      float* ys = &ls[(tid + st) * 5];
      float r[5]; int i = 0, j = 0;
#pragma unroll
      for (int q = 0; q < 5; q++) r[q] = (xs[i] <= ys[j]) ? xs[i++] : ys[j++];
#pragma unroll
      for (int q = 0; q < 5; q++) xs[q] = r[q];
    }
    __syncthreads();
  }
  if (tid == 0) atomicAdd(sig, sqrtf(ls[4]));
}

// ---------------- Kb = bf16(exp(-d2/(2 sigma^2))) --------------------------------
__global__ __launch_bounds__(256) void expk(const float* __restrict__ d2,
                                            unsigned short* __restrict__ Kb,
                                            const float* __restrict__ sig) {
  float sigma = (*sig) * (1.0f / NP);
  float c = -1.0f / (2.0f * sigma * sigma);
  size_t i = ((size_t)blockIdx.x * 256 + threadIdx.x) * 4;
  float4 v = *(const float4*)&d2[i];
  ushort4 o;
  o.x = f2b(expf(v.x * c)); o.y = f2b(expf(v.y * c));
  o.z = f2b(expf(v.z * c)); o.w = f2b(expf(v.w * c));
  *(ushort4*)&Kb[i] = o;
}

// ---------------- persistent loop kernel (no partials, 1 grid barrier/iter) ------
// 128 blocks x 512 threads (8 waves). Block owns rows R0=blk*32 (full K=4096).
// Wave w owns output cols w*32..+31; B (Yt) fragments load global->reg (wave-
// private); A (Kb rows) staged in LDS 512-wide chunks, double-buffered with
// register prefetch. Softmax via 32x256 LDS exchange. Yt double-buffered across
// iterations (read buf[iter&1], write other) -> one grid barrier per iter.
__global__ __launch_bounds__(512) void loop_k(const unsigned short* __restrict__ Kb,
                                              unsigned short* __restrict__ Yt0,
                                              unsigned short* __restrict__ Yt1,
                                              const float* __restrict__ unary,
                                              float* __restrict__ out,
                                              double* __restrict__ Ed,
                                              unsigned* __restrict__ flags,
                                              unsigned* __restrict__ gen) {
  const int tid = threadIdx.x, lane = tid & 63, wid = tid >> 6;
  const int blk = blockIdx.x;
  const int R0 = blk * 32;
  const int l15 = lane & 15, l16 = lane >> 4;
  constexpr int LDA = 520;  // 512 + 8 pad (1040B row stride)
  constexpr int LDP = 260;  // f32 words, +4 pad
  constexpr int LDY = 258;
  __shared__ __align__(16) unsigned short sA[2][32 * LDA];  // 2 x 33.3 KB
  __shared__ __align__(16) float P[32 * LDP];               // 33.3 KB
  __shared__ __align__(16) unsigned short yt[32 * LDY];     // 16.5 KB
  __shared__ double ered[8];
  float oldEf = __int_as_float(0x7f800000);

  for (int iter = 0; iter < MAXIT; ++iter) {
    const unsigned short* Yrd = (iter & 1) ? Yt1 : Yt0;
    unsigned short* Ywr = (iter & 1) ? Yt0 : Yt1;

    f32x4 acc[2][2];
#pragma unroll
    for (int m = 0; m < 2; m++)
#pragma unroll
      for (int n = 0; n < 2; n++) acc[m][n] = 0.0f;

    // prologue: prefetch A chunk 0 into regs
    uint4 pre[4];
#pragma unroll
    for (int j = 0; j < 4; ++j) {
      int u = j * 512 + tid, r = u >> 6, c = u & 63;
      pre[j] = *(const uint4*)&Kb[(size_t)(R0 + r) * NP + c * 8];
    }
    for (int ch = 0; ch < 8; ++ch) {
      unsigned short* buf = sA[ch & 1];
#pragma unroll
      for (int j = 0; j < 4; ++j) {
        int u = j * 512 + tid, r = u >> 6, c = u & 63;
        *(uint4*)&buf[r * LDA + c * 8] = pre[j];
      }
      __syncthreads();
      if (ch < 7) {
#pragma unroll
        for (int j = 0; j < 4; ++j) {
          int u = j * 512 + tid, r = u >> 6, c = u & 63;
          pre[j] = *(const uint4*)&Kb[(size_t)(R0 + r) * NP + (ch + 1) * 512 + c * 8];
        }
      }
#pragma unroll
      for (int sub = 0; sub < 8; ++sub) {
        const int kg = ch * 512 + sub * 64;
        bf16x8 bfv[2][2], afv[2][2];
#pragma unroll
        for (int n = 0; n < 2; ++n)
#pragma unroll
          for (int kk = 0; kk < 2; ++kk)
            bfv[n][kk] = *(const bf16x8*)&Yrd[(size_t)(wid * 32 + n * 16 + l15) * NP +
                                             kg + kk * 32 + l16 * 8];
#pragma unroll
        for (int m = 0; m < 2; ++m)
#pragma unroll
          for (int kk = 0; kk < 2; ++kk)
            afv[m][kk] = *(const bf16x8*)&buf[(m * 16 + l15) * LDA + sub * 64 +
                                              kk * 32 + l16 * 8];
#pragma unroll
        for (int kk = 0; kk < 2; ++kk)
#pragma unroll
          for (int m = 0; m < 2; ++m)
#pragma unroll
            for (int n = 0; n < 2; ++n)
              acc[m][n] = __builtin_amdgcn_mfma_f32_16x16x32_bf16(afv[m][kk], bfv[n][kk],
                                                                  acc[m][n], 0, 0, 0);
      }
      // no syncthreads here: double-buffered; one barrier per chunk (at top)
    }
    // store acc -> P (row = m*16+l16*4+j, col = wid*32+n*16+l15)
#pragma unroll
    for (int m = 0; m < 2; ++m)
#pragma unroll
      for (int n = 0; n < 2; ++n)
#pragma unroll
        for (int j = 0; j < 4; ++j)
          P[(m * 16 + l16 * 4 + j) * LDP + wid * 32 + n * 16 + l15] = acc[m][n][j];
    __syncthreads();

    // softmax: wave w handles rows wid*4 .. +3
    double ep = 0.0;
#pragma unroll
    for (int h = 0; h < 4; ++h) {
      const int r = wid * 4 + h;
      const int row = R0 + r;
      const int c0 = lane * 4;
      float4 p4 = *(const float4*)&P[r * LDP + c0];
      float pv[4] = {p4.x, p4.y, p4.z, p4.w};
      float4 u4 = *(const float4*)&unary[(size_t)row * NC + c0];
      float uu[4] = {u4.x, u4.y, u4.z, u4.w};
      float z[4];
#pragma unroll
      for (int q = 0; q < 4; ++q) z[q] = pv[q] - uu[q];
      float m = fmaxf(fmaxf(z[0], z[1]), fmaxf(z[2], z[3]));
#pragma unroll
      for (int o = 32; o >= 1; o >>= 1) m = fmaxf(m, __shfl_xor(m, o, 64));
      float e[4], ssum = 0.f;
#pragma unroll
      for (int q = 0; q < 4; ++q) { e[q] = expf(z[q] - m); ssum += e[q]; }
#pragma unroll
      for (int o = 32; o >= 1; o >>= 1) ssum += __shfl_xor(ssum, o, 64);
      float inv = 1.0f / ssum;
      float y[4];
#pragma unroll
      for (int q = 0; q < 4; ++q) {
        y[q] = e[q] * inv;
        ep += (double)(y[q] * (uu[q] - pv[q] + logf(fmaxf(y[q], 1e-20f))));
        yt[r * LDY + c0 + q] = f2b(y[q]);
      }
      float4 o4; o4.x = y[0]; o4.y = y[1]; o4.z = y[2]; o4.w = y[3];
      *(float4*)&out[(size_t)row * NC + c0] = o4;
    }
#pragma unroll
    for (int o = 32; o >= 1; o >>= 1) ep += __shfl_xor(ep, o, 64);
    if (lane == 0) ered[wid] = ep;
    __syncthreads();

    // flush transposed Yt: thread c<256 packs yt[0..31][c] -> Ywr[c][R0..R0+31]
    if (tid < 256) {
      unsigned v[16];
#pragma unroll
      for (int k = 0; k < 16; ++k) {
        unsigned lo = yt[(2 * k) * LDY + tid];
        unsigned hi = yt[(2 * k + 1) * LDY + tid];
        v[k] = lo | (hi << 16);
      }
      uint4* dst = (uint4*)&Ywr[(size_t)tid * NP + R0];
      dst[0] = make_uint4(v[0], v[1], v[2], v[3]);
      dst[1] = make_uint4(v[4], v[5], v[6], v[7]);
      dst[2] = make_uint4(v[8], v[9], v[10], v[11]);
      dst[3] = make_uint4(v[12], v[13], v[14], v[15]);
    }
    if (tid == 0) {
      double eblk = 0.0;
#pragma unroll
      for (int w = 0; w < 8; ++w) eblk += ered[w];
      atomicAdd(&Ed[iter], eblk);
    }
    gridbar(flags, gen, (unsigned)(iter + 1), tid, NBLK2);

    double Ec = __hip_atomic_load(&Ed[iter], __ATOMIC_RELAXED, __HIP_MEMORY_SCOPE_AGENT);
    float Ef = (float)Ec;
    if (iter > 1 && fabsf(Ef - oldEf) <= 1e-8f * fabsf(oldEf)) break;  // frozen
    oldEf = Ef;
  }
}

extern "C" void kernel_launch(void* const* d_in, const int* in_sizes, int n_in,
                              void* d_out, int out_size, void* d_ws, size_t ws_size,
                              hipStream_t stream) {
  const float* x = (const float*)d_in[0];
  const float* W = (const float*)d_in[1];
  const float* bias = (const float*)d_in[2];
  float* out = (float*)d_out;

  char* p = (char*)d_ws;
  auto take = [&](size_t bytes) {
    char* r = p;
    p += (bytes + 255) & ~(size_t)255;
    return r;
  };
  float* d2          = (float*)take((size_t)NP * NP * 4);          // 64 MB
  unsigned short* Kb = (unsigned short*)take((size_t)NP * NP * 2); // 32 MB
  unsigned short* F  = (unsigned short*)take((size_t)NP * DIMF * 2);
  unsigned short* xb = (unsigned short*)take((size_t)NP * DIMF * 2);
  unsigned short* Wb = (unsigned short*)take((size_t)NC * DIMF * 2);
  unsigned short* Yt0 = (unsigned short*)take((size_t)NC * NP * 2);
  unsigned short* Yt1 = (unsigned short*)take((size_t)NC * NP * 2);
  float* logits = (float*)take((size_t)NP * NC * 4);
  float* unary  = (float*)take((size_t)NP * NC * 4);
  float* sqF    = (float*)take((size_t)NP * 4);
  float* sig    = (float*)take(256);
  double* Ed    = (double*)take(MAXIT * 8);
  unsigned* flags = (unsigned*)take((size_t)256 * 32 * 4);
  unsigned* gen   = (unsigned*)take(256);

  initk<<<1, 256, 0, stream>>>(Ed, sig, flags, gen);
  castk<<<512, 256, 0, stream>>>(W, Wb);
  rownorm<<<NP, 256, 0, stream>>>(x, F, xb, sqF);
  // logits = x @ W^T + b
  gemm_bt<64, 64, 4, 1, 0><<<dim3(64, 4), 256, 0, stream>>>(xb, Wb, logits, NP, NC, DIMF, bias);
  unary_k<<<1024, 256, 0, stream>>>(logits, unary);
  smax0<<<256, 256, 0, stream>>>(unary, out, Yt0);
  // d2 = max(sq_i + sq_j - 2 F F^T, 0)
  gemm_bt<128, 128, 2, 2, 1><<<dim3(32, 32), 256, 0, stream>>>(F, F, d2, NP, NP, DIMF, sqF);
  kth_k<<<NP, 256, 0, stream>>>(d2, sig);
  expk<<<16384, 256, 0, stream>>>(d2, Kb, sig);
  // laplacian loop: persistent kernel, homemade grid barrier (128 co-resident blocks)
  loop_k<<<NBLK2, 512, 0, stream>>>(Kb, Yt0, Yt1, unary, out, Ed, flags, gen);
}

// Round 7
// 626.713 us; speedup vs baseline: 1.5713x; 1.2485x over previous
//
#include <hip/hip_runtime.h>
#include <cstdint>

#define NP 4096   // points
#define DIMF 2048 // feature dim
#define NC 256    // classes
#define MAXIT 100
#define NBLK2 256 // loop kernel grid size (1 block/CU, co-resident)

typedef __bf16 bf16x8 __attribute__((ext_vector_type(8)));
typedef float f32x4 __attribute__((ext_vector_type(4)));

__device__ inline unsigned short f2b(float f) {
  union { float f; unsigned u; } v; v.f = f;
  unsigned r = v.u + 0x7fffu + ((v.u >> 16) & 1u);  // RNE
  return (unsigned short)(r >> 16);
}
__device__ inline float b2f(unsigned short u) {
  union { unsigned u; float f; } v; v.u = ((unsigned)u) << 16;
  return v.f;
}

// ---- contention-free grid barrier (homemade; blocks must be co-resident) ----
__device__ __forceinline__ void gridbar(unsigned* flags, unsigned* gen,
                                        unsigned phase, int tid, int nblk) {
  __syncthreads();
  if (blockIdx.x == 0) {
    if (tid >= 1 && tid < nblk) {
      while (__hip_atomic_load(&flags[tid * 32], __ATOMIC_ACQUIRE,
                               __HIP_MEMORY_SCOPE_AGENT) < phase)
        __builtin_amdgcn_s_sleep(1);
    }
    __syncthreads();
    if (tid == 0)
      __hip_atomic_store(gen, phase, __ATOMIC_RELEASE, __HIP_MEMORY_SCOPE_AGENT);
  } else {
    if (tid == 0) {
      __hip_atomic_store(&flags[blockIdx.x * 32], phase, __ATOMIC_RELEASE,
                         __HIP_MEMORY_SCOPE_AGENT);
      while (__hip_atomic_load(gen, __ATOMIC_ACQUIRE,
                               __HIP_MEMORY_SCOPE_AGENT) < phase)
        __builtin_amdgcn_s_sleep(1);
    }
  }
  __syncthreads();
}

// ---------------- init (ws poisoned 0xAA before every call) ----------------
__global__ __launch_bounds__(256) void initk(double* Ed, float* sig,
                                             unsigned* flags, unsigned* gen) {
  int t = threadIdx.x;
  if (t < MAXIT) Ed[t] = 0.0;
  if (t == 0) { *sig = 0.0f; *gen = 0u; }
  for (int i = t; i < NBLK2 * 32; i += 256) flags[i] = 0u;
}

// ---------------- W f32 -> bf16 ----------------
__global__ __launch_bounds__(256) void castk(const float* __restrict__ W,
                                             unsigned short* __restrict__ Wb) {
  size_t i = ((size_t)blockIdx.x * 256 + threadIdx.x) * 4;
  float4 v = *(const float4*)&W[i];
  ushort4 o; o.x = f2b(v.x); o.y = f2b(v.y); o.z = f2b(v.z); o.w = f2b(v.w);
  *(ushort4*)&Wb[i] = o;
}

// ---------------- row-normalize x -> F(bf16), x -> xb(bf16), sqF ----------------
__global__ __launch_bounds__(256) void rownorm(const float* __restrict__ x,
                                               unsigned short* __restrict__ F,
                                               unsigned short* __restrict__ xb,
                                               float* __restrict__ sqF) {
  const int row = blockIdx.x, tid = threadIdx.x;
  const float* rp = x + (size_t)row * DIMF;
  float4 a = *(const float4*)&rp[tid * 8];
  float4 b = *(const float4*)&rp[tid * 8 + 4];
  float f[8] = {a.x, a.y, a.z, a.w, b.x, b.y, b.z, b.w};
  float s = 0.f;
#pragma unroll
  for (int k = 0; k < 8; k++) s += f[k] * f[k];
  __shared__ float red[256];
  red[tid] = s; __syncthreads();
  for (int st = 128; st >= 1; st >>= 1) {
    if (tid < st) red[tid] += red[tid + st];
    __syncthreads();
  }
  float inv = 1.0f / sqrtf(red[0]);
  __syncthreads();
  unsigned short fb[8], xbv[8];
  float s2 = 0.f;
#pragma unroll
  for (int k = 0; k < 8; k++) {
    fb[k] = f2b(f[k] * inv);
    xbv[k] = f2b(f[k]);
    float q = b2f(fb[k]);
    s2 += q * q;
  }
  *(ushort4*)&F[(size_t)row * DIMF + tid * 8]      = *(ushort4*)&fb[0];
  *(ushort4*)&F[(size_t)row * DIMF + tid * 8 + 4]  = *(ushort4*)&fb[4];
  *(ushort4*)&xb[(size_t)row * DIMF + tid * 8]     = *(ushort4*)&xbv[0];
  *(ushort4*)&xb[(size_t)row * DIMF + tid * 8 + 4] = *(ushort4*)&xbv[4];
  red[tid] = s2; __syncthreads();
  for (int st = 128; st >= 1; st >>= 1) {
    if (tid < st) red[tid] += red[tid + st];
    __syncthreads();
  }
  if (tid == 0) sqF[row] = red[0];
}

// ---------------- r1-validated reg-staged GEMM (BK=32): C = A[M,K]*B[N,K]^T ----
template <int BM, int BN, int WR, int WC, int EPI>
__global__ __launch_bounds__(256) void gemm_bt(const unsigned short* __restrict__ A,
                                               const unsigned short* __restrict__ B,
                                               float* __restrict__ C,
                                               int M, int N, int K,
                                               const float* __restrict__ aux) {
  constexpr int WM = BM / WR, WN = BN / WC;
  constexpr int TM = WM / 16, TN = WN / 16;
  constexpr int LDT = 40;
  __shared__ __align__(16) unsigned short sA[BM * LDT];
  __shared__ __align__(16) unsigned short sB[BN * LDT];
  const int tid = threadIdx.x;
  const int wid = tid >> 6, lane = tid & 63;
  const int wr = wid / WC, wc = wid % WC;
  const int l15 = lane & 15, l16 = lane >> 4;
  const int bm = blockIdx.x * BM, bn = blockIdx.y * BN;
  f32x4 acc[TM][TN];
#pragma unroll
  for (int m = 0; m < TM; m++)
#pragma unroll
    for (int n = 0; n < TN; n++) acc[m][n] = 0.0f;

  for (int k0 = 0; k0 < K; k0 += 32) {
    for (int i = tid; i < BM * 4; i += 256) {
      int r = i >> 2, ch = i & 3;
      *(uint4*)&sA[r * LDT + ch * 8] =
          *(const uint4*)&A[(size_t)(bm + r) * K + k0 + ch * 8];
    }
    for (int i = tid; i < BN * 4; i += 256) {
      int r = i >> 2, ch = i & 3;
      *(uint4*)&sB[r * LDT + ch * 8] =
          *(const uint4*)&B[(size_t)(bn + r) * K + k0 + ch * 8];
    }
    __syncthreads();
    bf16x8 af[TM], bf[TN];
#pragma unroll
    for (int m = 0; m < TM; m++)
      af[m] = *(const bf16x8*)&sA[(wr * WM + m * 16 + l15) * LDT + l16 * 8];
#pragma unroll
    for (int n = 0; n < TN; n++)
      bf[n] = *(const bf16x8*)&sB[(wc * WN + n * 16 + l15) * LDT + l16 * 8];
#pragma unroll
    for (int m = 0; m < TM; m++)
#pragma unroll
      for (int n = 0; n < TN; n++)
        acc[m][n] = __builtin_amdgcn_mfma_f32_16x16x32_bf16(af[m], bf[n], acc[m][n], 0, 0, 0);
    __syncthreads();
  }
#pragma unroll
  for (int m = 0; m < TM; m++) {
    int row0 = bm + wr * WM + m * 16 + l16 * 4;
#pragma unroll
    for (int n = 0; n < TN; n++) {
      int col = bn + wc * WN + n * 16 + l15;
#pragma unroll
      for (int j = 0; j < 4; j++) {
        int row = row0 + j;
        float v = acc[m][n][j];
        if (EPI == 0) {
          C[(size_t)row * NC + col] = v + aux[col];
        } else {
          float d = aux[row] + aux[col] - 2.0f * v;
          C[(size_t)row * NP + col] = fmaxf(d, 0.0f);
        }
      }
    }
  }
}

// ---------------- unary = -log(softmax(logits)+1e-10), one wave per row ----------
__global__ __launch_bounds__(256) void unary_k(const float* __restrict__ logits,
                                               float* __restrict__ unary) {
  const int wid = threadIdx.x >> 6, lane = threadIdx.x & 63;
  const int row = blockIdx.x * 4 + wid;
  const float* lp = logits + (size_t)row * NC;
  float v[4];
#pragma unroll
  for (int j = 0; j < 4; j++) v[j] = lp[lane + 64 * j];
  float m = fmaxf(fmaxf(v[0], v[1]), fmaxf(v[2], v[3]));
#pragma unroll
  for (int o = 32; o >= 1; o >>= 1) m = fmaxf(m, __shfl_xor(m, o, 64));
  float e[4], s = 0.f;
#pragma unroll
  for (int j = 0; j < 4; j++) { e[j] = expf(v[j] - m); s += e[j]; }
#pragma unroll
  for (int o = 32; o >= 1; o >>= 1) s += __shfl_xor(s, o, 64);
  float* up = unary + (size_t)row * NC;
#pragma unroll
  for (int j = 0; j < 4; j++) up[lane + 64 * j] = -logf(e[j] / s + 1e-10f);
}

// ---- Y2 layout: class c, point k -> ((c>>5)<<17) + ((k>>3)*32 + (c&31))*8 + (k&7)
// (32-class tiles; within tile k8-major; 8 consecutive k per 16B chunk)

// ---------------- Y0 = softmax(-unary) -> out(f32), Y2(bf16 tiled) ----------
__global__ __launch_bounds__(256) void smax0(const float* __restrict__ unary,
                                             float* __restrict__ Yout,
                                             unsigned short* __restrict__ Yt) {
  const int tid = threadIdx.x;
  const int wid = tid >> 6, lane = tid & 63;
  const int rb = blockIdx.x;  // 16 rows per block
  __shared__ __align__(16) unsigned short yt[256][24];
  for (int rr = wid; rr < 16; rr += 4) {
    const int row = rb * 16 + rr;
    float z[4];
#pragma unroll
    for (int j = 0; j < 4; j++) z[j] = -unary[(size_t)row * NC + lane + 64 * j];
    float m = fmaxf(fmaxf(z[0], z[1]), fmaxf(z[2], z[3]));
#pragma unroll
    for (int o = 32; o >= 1; o >>= 1) m = fmaxf(m, __shfl_xor(m, o, 64));
    float e[4], s = 0.f;
#pragma unroll
    for (int j = 0; j < 4; j++) { e[j] = expf(z[j] - m); s += e[j]; }
#pragma unroll
    for (int o = 32; o >= 1; o >>= 1) s += __shfl_xor(s, o, 64);
#pragma unroll
    for (int j = 0; j < 4; j++) {
      int c = lane + 64 * j;
      float y = e[j] / s;
      Yout[(size_t)row * NC + c] = y;
      yt[c][rr] = f2b(y);
    }
  }
  __syncthreads();
  const int c = tid;
#pragma unroll
  for (int r8 = 0; r8 < 2; ++r8) {
    unsigned v[4];
#pragma unroll
    for (int k = 0; k < 4; ++k) {
      unsigned lo = yt[c][r8 * 8 + 2 * k];
      unsigned hi = yt[c][r8 * 8 + 2 * k + 1];
      v[k] = lo | (hi << 16);
    }
    size_t off = ((size_t)(c >> 5) << 17) +
                 (size_t)(((rb * 2 + r8) * 32 + (c & 31)) * 8);
    *(uint4*)&Yt[off] = make_uint4(v[0], v[1], v[2], v[3]);
  }
}

// ---------------- per-row 5th-smallest d2 -> atomicAdd(sqrt) into sig ------------
__global__ __launch_bounds__(256) void kth_k(const float* __restrict__ d2,
                                             float* __restrict__ sig) {
  const int row = blockIdx.x, tid = threadIdx.x;
  const float* rp = d2 + (size_t)row * NP;
  float b[5];
#pragma unroll
  for (int q = 0; q < 5; q++) b[q] = __int_as_float(0x7f800000);
  for (int s = 0; s < 16; s++) {
    float v = rp[tid + 256 * s];
    if (v < b[4]) {
      b[4] = v;
#pragma unroll
      for (int q = 4; q > 0; q--)
        if (b[q] < b[q - 1]) { float t = b[q]; b[q] = b[q - 1]; b[q - 1] = t; }
    }
  }
  __shared__ float ls[256 * 5];
#pragma unroll
  for (int q = 0; q < 5; q++) ls[tid * 5 + q] = b[q];
  __syncthreads();
  for (int st = 128; st >= 1; st >>= 1) {
    if (tid < st) {
      float* xs = &ls[tid * 5];
      float* ys = &ls[(tid + st) * 5];
      float r[5]; int i = 0, j = 0;
#pragma unroll
      for (int q = 0; q < 5; q++) r[q] = (xs[i] <= ys[j]) ? xs[i++] : ys[j++];
#pragma unroll
      for (int q = 0; q < 5; q++) xs[q] = r[q];
    }
    __syncthreads();
  }
  if (tid == 0) atomicAdd(sig, sqrtf(ls[4]));
}

// ---------------- Kb = bf16(exp(-d2/(2 sigma^2))) --------------------------------
__global__ __launch_bounds__(256) void expk(const float* __restrict__ d2,
                                            unsigned short* __restrict__ Kb,
                                            const float* __restrict__ sig) {
  float sigma = (*sig) * (1.0f / NP);
  float c = -1.0f / (2.0f * sigma * sigma);
  size_t i = ((size_t)blockIdx.x * 256 + threadIdx.x) * 4;
  float4 v = *(const float4*)&d2[i];
  ushort4 o;
  o.x = f2b(expf(v.x * c)); o.y = f2b(expf(v.y * c));
  o.z = f2b(expf(v.z * c)); o.w = f2b(expf(v.w * c));
  *(ushort4*)&Kb[i] = o;
}

// ---------------- persistent loop kernel v3 ---------------------------------------
// 256 blocks x 512 threads (8 waves), 1/CU. Block owns 16 rows, full K=4096.
// Wave w owns output cols w*32..+31; Y2 fragments load global->reg (dense 16B/lane,
// one-sub-ahead prefetch); Kb rows staged in LDS 512-wide chunks, double-buffered.
// Softmax via LDS exchange; Y double-buffered across iters; 1 grid barrier/iter.
__global__ __launch_bounds__(512) void loop_k(const unsigned short* __restrict__ Kb,
                                              unsigned short* __restrict__ Yt0,
                                              unsigned short* __restrict__ Yt1,
                                              const float* __restrict__ unary,
                                              float* __restrict__ out,
                                              double* __restrict__ Ed,
                                              unsigned* __restrict__ flags,
                                              unsigned* __restrict__ gen) {
  const int tid = threadIdx.x, lane = tid & 63, wid = tid >> 6;
  const int blk = blockIdx.x;
  const int R0 = blk * 16;
  const int l15 = lane & 15, l16 = lane >> 4;
  constexpr int LDA = 520;  // bf16 elems (512 + 8 pad)
  constexpr int LDP = 260;  // f32 (1040B row: 16B-aligned)
  constexpr int LDY = 258;
  __shared__ __align__(16) unsigned short sA[2][16 * LDA];  // 2 x 16.6 KB
  __shared__ __align__(16) float P[16 * LDP];               // 16.6 KB
  __shared__ __align__(16) unsigned short yt[16 * LDY];     // 8.3 KB
  __shared__ double ered[8];
  float oldEf = __int_as_float(0x7f800000);

  const int b0 = l15 * 8;          // Y2 elem offset, n=0
  const int b1 = (16 + l15) * 8;   // n=1
  // staging indices (2 x uint4 per thread per chunk)
  const int sr0 = tid >> 6, sc0 = tid & 63;
  const int sr1 = (512 + tid) >> 6, sc1 = tid & 63;

  for (int iter = 0; iter < MAXIT; ++iter) {
    const unsigned short* Yrd = ((iter & 1) ? Yt1 : Yt0) + ((size_t)wid << 17);
    unsigned short* Ywr = (iter & 1) ? Yt0 : Yt1;

    f32x4 acc[2];
    acc[0] = 0.0f; acc[1] = 0.0f;

    // prologue: prefetch Kb chunk 0 + Y2 (ch=0,sub=0)
    uint4 pre0 = *(const uint4*)&Kb[(size_t)(R0 + sr0) * NP + sc0 * 8];
    uint4 pre1 = *(const uint4*)&Kb[(size_t)(R0 + sr1) * NP + sc1 * 8];
    bf16x8 nb[2][2], cb[2][2];
    {
      const int kb8 = 0;
      nb[0][0] = *(const bf16x8*)&Yrd[(size_t)(kb8 + l16) * 256 + b0];
      nb[0][1] = *(const bf16x8*)&Yrd[(size_t)(kb8 + 4 + l16) * 256 + b0];
      nb[1][0] = *(const bf16x8*)&Yrd[(size_t)(kb8 + l16) * 256 + b1];
      nb[1][1] = *(const bf16x8*)&Yrd[(size_t)(kb8 + 4 + l16) * 256 + b1];
    }

    for (int ch = 0; ch < 8; ++ch) {
      unsigned short* buf = sA[ch & 1];
      *(uint4*)&buf[sr0 * LDA + sc0 * 8] = pre0;
      *(uint4*)&buf[sr1 * LDA + sc1 * 8] = pre1;
      __syncthreads();
      if (ch < 7) {
        pre0 = *(const uint4*)&Kb[(size_t)(R0 + sr0) * NP + (ch + 1) * 512 + sc0 * 8];
        pre1 = *(const uint4*)&Kb[(size_t)(R0 + sr1) * NP + (ch + 1) * 512 + sc1 * 8];
      }
#pragma unroll
      for (int sub = 0; sub < 8; ++sub) {
#pragma unroll
        for (int n = 0; n < 2; ++n)
#pragma unroll
          for (int kk = 0; kk < 2; ++kk) cb[n][kk] = nb[n][kk];
        // prefetch next sub (or next chunk's sub 0)
        if (!(ch == 7 && sub == 7)) {
          const int ns = (sub < 7) ? (ch * 64 + (sub + 1) * 8) : ((ch + 1) * 64);
          nb[0][0] = *(const bf16x8*)&Yrd[(size_t)(ns + l16) * 256 + b0];
          nb[0][1] = *(const bf16x8*)&Yrd[(size_t)(ns + 4 + l16) * 256 + b0];
          nb[1][0] = *(const bf16x8*)&Yrd[(size_t)(ns + l16) * 256 + b1];
          nb[1][1] = *(const bf16x8*)&Yrd[(size_t)(ns + 4 + l16) * 256 + b1];
        }
        bf16x8 af[2];
        af[0] = *(const bf16x8*)&buf[l15 * LDA + sub * 64 + l16 * 8];
        af[1] = *(const bf16x8*)&buf[l15 * LDA + sub * 64 + 32 + l16 * 8];
#pragma unroll
        for (int kk = 0; kk < 2; ++kk)
#pragma unroll
          for (int n = 0; n < 2; ++n)
            acc[n] = __builtin_amdgcn_mfma_f32_16x16x32_bf16(af[kk], cb[n][kk], acc[n], 0, 0, 0);
      }
      __syncthreads();
    }
    // acc -> P: row = l16*4+j, col = wid*32 + n*16 + l15
#pragma unroll
    for (int n = 0; n < 2; ++n)
#pragma unroll
      for (int j = 0; j < 4; ++j)
        P[(l16 * 4 + j) * LDP + wid * 32 + n * 16 + l15] = acc[n][j];
    __syncthreads();

    // softmax: wave w handles rows wid*2 .. +1
    double ep = 0.0;
#pragma unroll
    for (int h = 0; h < 2; ++h) {
      const int r = wid * 2 + h;
      const int row = R0 + r;
      const int c0 = lane * 4;
      float4 p4 = *(const float4*)&P[r * LDP + c0];
      float pv[4] = {p4.x, p4.y, p4.z, p4.w};
      float4 u4 = *(const float4*)&unary[(size_t)row * NC + c0];
      float uu[4] = {u4.x, u4.y, u4.z, u4.w};
      float z[4];
#pragma unroll
      for (int q = 0; q < 4; ++q) z[q] = pv[q] - uu[q];
      float m = fmaxf(fmaxf(z[0], z[1]), fmaxf(z[2], z[3]));
#pragma unroll
      for (int o = 32; o >= 1; o >>= 1) m = fmaxf(m, __shfl_xor(m, o, 64));
      float e[4], ssum = 0.f;
#pragma unroll
      for (int q = 0; q < 4; ++q) { e[q] = expf(z[q] - m); ssum += e[q]; }
#pragma unroll
      for (int o = 32; o >= 1; o >>= 1) ssum += __shfl_xor(ssum, o, 64);
      float inv = 1.0f / ssum;
      float y[4];
#pragma unroll
      for (int q = 0; q < 4; ++q) {
        y[q] = e[q] * inv;
        ep += (double)(y[q] * (uu[q] - pv[q] + logf(fmaxf(y[q], 1e-20f))));
        yt[r * LDY + c0 + q] = f2b(y[q]);
      }
      float4 o4; o4.x = y[0]; o4.y = y[1]; o4.z = y[2]; o4.w = y[3];
      *(float4*)&out[(size_t)row * NC + c0] = o4;
    }
#pragma unroll
    for (int o = 32; o >= 1; o >>= 1) ep += __shfl_xor(ep, o, 64);
    if (lane == 0) ered[wid] = ep;
    __syncthreads();

    // flush Y2: thread (c = tid&255, r8 = tid>>8) packs 8 rows of class c
    {
      const int c = tid & 255, r8 = tid >> 8;
      unsigned v[4];
#pragma unroll
      for (int k = 0; k < 4; ++k) {
        unsigned lo = yt[(r8 * 8 + 2 * k) * LDY + c];
        unsigned hi = yt[(r8 * 8 + 2 * k + 1) * LDY + c];
        v[k] = lo | (hi << 16);
      }
      size_t off = ((size_t)(c >> 5) << 17) +
                   (size_t)(((blk * 2 + r8) * 32 + (c & 31)) * 8);
      *(uint4*)&Ywr[off] = make_uint4(v[0], v[1], v[2], v[3]);
    }
    if (tid == 0) {
      double eblk = 0.0;
#pragma unroll
      for (int w = 0; w < 8; ++w) eblk += ered[w];
      atomicAdd(&Ed[iter], eblk);
    }
    gridbar(flags, gen, (unsigned)(iter + 1), tid, NBLK2);

    double Ec = __hip_atomic_load(&Ed[iter], __ATOMIC_RELAXED, __HIP_MEMORY_SCOPE_AGENT);
    float Ef = (float)Ec;
    if (iter > 1 && fabsf(Ef - oldEf) <= 1e-8f * fabsf(oldEf)) break;  // frozen
    oldEf = Ef;
  }
}

extern "C" void kernel_launch(void* const* d_in, const int* in_sizes, int n_in,
                              void* d_out, int out_size, void* d_ws, size_t ws_size,
                              hipStream_t stream) {
  const float* x = (const float*)d_in[0];
  const float* W = (const float*)d_in[1];
  const float* bias = (const float*)d_in[2];
  float* out = (float*)d_out;

  char* p = (char*)d_ws;
  auto take = [&](size_t bytes) {
    char* r = p;
    p += (bytes + 255) & ~(size_t)255;
    return r;
  };
  float* d2          = (float*)take((size_t)NP * NP * 4);          // 64 MB
  unsigned short* Kb = (unsigned short*)take((size_t)NP * NP * 2); // 32 MB
  unsigned short* F  = (unsigned short*)take((size_t)NP * DIMF * 2);
  unsigned short* xb = (unsigned short*)take((size_t)NP * DIMF * 2);
  unsigned short* Wb = (unsigned short*)take((size_t)NC * DIMF * 2);
  unsigned short* Yt0 = (unsigned short*)take((size_t)NC * NP * 2);
  unsigned short* Yt1 = (unsigned short*)take((size_t)NC * NP * 2);
  float* logits = (float*)take((size_t)NP * NC * 4);
  float* unary  = (float*)take((size_t)NP * NC * 4);
  float* sqF    = (float*)take((size_t)NP * 4);
  float* sig    = (float*)take(256);
  double* Ed    = (double*)take(MAXIT * 8);
  unsigned* flags = (unsigned*)take((size_t)NBLK2 * 32 * 4);
  unsigned* gen   = (unsigned*)take(256);

  initk<<<1, 256, 0, stream>>>(Ed, sig, flags, gen);
  castk<<<512, 256, 0, stream>>>(W, Wb);
  rownorm<<<NP, 256, 0, stream>>>(x, F, xb, sqF);
  // logits = x @ W^T + b
  gemm_bt<64, 64, 4, 1, 0><<<dim3(64, 4), 256, 0, stream>>>(xb, Wb, logits, NP, NC, DIMF, bias);
  unary_k<<<1024, 256, 0, stream>>>(logits, unary);
  smax0<<<256, 256, 0, stream>>>(unary, out, Yt0);
  // d2 = max(sq_i + sq_j - 2 F F^T, 0)
  gemm_bt<128, 128, 2, 2, 1><<<dim3(32, 32), 256, 0, stream>>>(F, F, d2, NP, NP, DIMF, sqF);
  kth_k<<<NP, 256, 0, stream>>>(d2, sig);
  expk<<<16384, 256, 0, stream>>>(d2, Kb, sig);
  // laplacian loop: persistent kernel, homemade grid barrier (256 co-resident blocks)
  loop_k<<<NBLK2, 512, 0, stream>>>(Kb, Yt0, Yt1, unary, out, Ed, flags, gen);
}

// Round 8
// 557.262 us; speedup vs baseline: 1.7671x; 1.1246x over previous
//
#include <hip/hip_runtime.h>
#include <cstdint>

#define NP 4096   // points
#define DIMF 2048 // feature dim
#define NC 256    // classes
#define MAXIT 100
#define NBLK2 256 // loop kernel grid size (1 block/CU, co-resident)

typedef __bf16 bf16x8 __attribute__((ext_vector_type(8)));
typedef float f32x4 __attribute__((ext_vector_type(4)));

__device__ inline unsigned short f2b(float f) {
  union { float f; unsigned u; } v; v.f = f;
  unsigned r = v.u + 0x7fffu + ((v.u >> 16) & 1u);  // RNE
  return (unsigned short)(r >> 16);
}
__device__ inline float b2f(unsigned short u) {
  union { unsigned u; float f; } v; v.u = ((unsigned)u) << 16;
  return v.f;
}

// async global->LDS, 16 B per lane (linear dest: wave base + lane*16)
__device__ __forceinline__ void g2lds16(const void* g, void* l) {
  __builtin_amdgcn_global_load_lds(
      (const __attribute__((address_space(1))) unsigned int*)g,
      (__attribute__((address_space(3))) unsigned int*)l, 16, 0, 0);
}

// ---- contention-free grid barrier (homemade; blocks must be co-resident) ----
__device__ __forceinline__ void gridbar(unsigned* flags, unsigned* gen,
                                        unsigned phase, int tid, int nblk) {
  __syncthreads();
  if (blockIdx.x == 0) {
    if (tid >= 1 && tid < nblk) {
      while (__hip_atomic_load(&flags[tid * 32], __ATOMIC_ACQUIRE,
                               __HIP_MEMORY_SCOPE_AGENT) < phase)
        __builtin_amdgcn_s_sleep(1);
    }
    __syncthreads();
    if (tid == 0)
      __hip_atomic_store(gen, phase, __ATOMIC_RELEASE, __HIP_MEMORY_SCOPE_AGENT);
  } else {
    if (tid == 0) {
      __hip_atomic_store(&flags[blockIdx.x * 32], phase, __ATOMIC_RELEASE,
                         __HIP_MEMORY_SCOPE_AGENT);
      while (__hip_atomic_load(gen, __ATOMIC_ACQUIRE,
                               __HIP_MEMORY_SCOPE_AGENT) < phase)
        __builtin_amdgcn_s_sleep(1);
    }
  }
  __syncthreads();
}

// ---------------- init (ws poisoned 0xAA before every call) ----------------
__global__ __launch_bounds__(256) void initk(double* Ed, float* sig,
                                             unsigned* flags, unsigned* gen) {
  int t = threadIdx.x;
  if (t < MAXIT) Ed[t] = 0.0;
  if (t == 0) { *sig = 0.0f; *gen = 0u; }
  for (int i = t; i < NBLK2 * 32; i += 256) flags[i] = 0u;
}

// ---------------- W f32 -> bf16 ----------------
__global__ __launch_bounds__(256) void castk(const float* __restrict__ W,
                                             unsigned short* __restrict__ Wb) {
  size_t i = ((size_t)blockIdx.x * 256 + threadIdx.x) * 4;
  float4 v = *(const float4*)&W[i];
  ushort4 o; o.x = f2b(v.x); o.y = f2b(v.y); o.z = f2b(v.z); o.w = f2b(v.w);
  *(ushort4*)&Wb[i] = o;
}

// ---------------- row-normalize x -> F(bf16), x -> xb(bf16), sqF ----------------
__global__ __launch_bounds__(256) void rownorm(const float* __restrict__ x,
                                               unsigned short* __restrict__ F,
                                               unsigned short* __restrict__ xb,
                                               float* __restrict__ sqF) {
  const int row = blockIdx.x, tid = threadIdx.x;
  const float* rp = x + (size_t)row * DIMF;
  float4 a = *(const float4*)&rp[tid * 8];
  float4 b = *(const float4*)&rp[tid * 8 + 4];
  float f[8] = {a.x, a.y, a.z, a.w, b.x, b.y, b.z, b.w};
  float s = 0.f;
#pragma unroll
  for (int k = 0; k < 8; k++) s += f[k] * f[k];
  __shared__ float red[256];
  red[tid] = s; __syncthreads();
  for (int st = 128; st >= 1; st >>= 1) {
    if (tid < st) red[tid] += red[tid + st];
    __syncthreads();
  }
  float inv = 1.0f / sqrtf(red[0]);
  __syncthreads();
  unsigned short fb[8], xbv[8];
  float s2 = 0.f;
#pragma unroll
  for (int k = 0; k < 8; k++) {
    fb[k] = f2b(f[k] * inv);
    xbv[k] = f2b(f[k]);
    float q = b2f(fb[k]);
    s2 += q * q;
  }
  *(ushort4*)&F[(size_t)row * DIMF + tid * 8]      = *(ushort4*)&fb[0];
  *(ushort4*)&F[(size_t)row * DIMF + tid * 8 + 4]  = *(ushort4*)&fb[4];
  *(ushort4*)&xb[(size_t)row * DIMF + tid * 8]     = *(ushort4*)&xbv[0];
  *(ushort4*)&xb[(size_t)row * DIMF + tid * 8 + 4] = *(ushort4*)&xbv[4];
  red[tid] = s2; __syncthreads();
  for (int st = 128; st >= 1; st >>= 1) {
    if (tid < st) red[tid] += red[tid + st];
    __syncthreads();
  }
  if (tid == 0) sqF[row] = red[0];
}

// ---------------- m97-style GEMM: C[M,N] = A[M,K]*B[N,K]^T, BK=32, gload_lds ----
// 256 threads = 4 waves (2x2). TM=BM/32, TN=BN/32. Linear LDS (LDT=32), as m97.
// EPI 0: C = acc + aux[col]  (logits+bias)   EPI 1: C = max(aux[row]+aux[col]-2acc,0)
template <int BM, int BN, int EPI>
__global__ __launch_bounds__(256) void gemm2(const unsigned short* __restrict__ A,
                                             const unsigned short* __restrict__ B,
                                             float* __restrict__ C,
                                             int M, int N, int K,
                                             const float* __restrict__ aux) {
  constexpr int TM = BM / 32, TN = BN / 32;
  __shared__ __align__(16) unsigned short sA[BM * 32];
  __shared__ __align__(16) unsigned short sB[BN * 32];
  const int tid = threadIdx.x, lane = tid & 63, wid = tid >> 6;
  const int wr = wid >> 1, wc = wid & 1;
  const int l15 = lane & 15, l16 = lane >> 4;
  const int bm = blockIdx.x * BM, bn = blockIdx.y * BN;
  f32x4 acc[TM][TN];
#pragma unroll
  for (int m = 0; m < TM; m++)
#pragma unroll
    for (int n = 0; n < TN; n++) acc[m][n] = 0.0f;

  for (int k0 = 0; k0 < K; k0 += 32) {
#pragma unroll
    for (int j = 0; j < BM / 64; ++j) {
      int u = j * 256 + tid, r = u >> 2, c = u & 3;
      g2lds16(&A[(size_t)(bm + r) * K + k0 + c * 8], &sA[u * 8]);
    }
#pragma unroll
    for (int j = 0; j < BN / 64; ++j) {
      int u = j * 256 + tid, r = u >> 2, c = u & 3;
      g2lds16(&B[(size_t)(bn + r) * K + k0 + c * 8], &sB[u * 8]);
    }
    __syncthreads();
    bf16x8 af[TM], bf[TN];
#pragma unroll
    for (int m = 0; m < TM; m++)
      af[m] = *(const bf16x8*)&sA[(wr * TM * 16 + m * 16 + l15) * 32 + l16 * 8];
#pragma unroll
    for (int n = 0; n < TN; n++)
      bf[n] = *(const bf16x8*)&sB[(wc * TN * 16 + n * 16 + l15) * 32 + l16 * 8];
#pragma unroll
    for (int m = 0; m < TM; m++)
#pragma unroll
      for (int n = 0; n < TN; n++)
        acc[m][n] = __builtin_amdgcn_mfma_f32_16x16x32_bf16(af[m], bf[n], acc[m][n], 0, 0, 0);
    __syncthreads();
  }
#pragma unroll
  for (int m = 0; m < TM; m++) {
    int row0 = bm + wr * TM * 16 + m * 16 + l16 * 4;
#pragma unroll
    for (int n = 0; n < TN; n++) {
      int col = bn + wc * TN * 16 + n * 16 + l15;
#pragma unroll
      for (int j = 0; j < 4; j++) {
        int row = row0 + j;
        float v = acc[m][n][j];
        if (EPI == 0) {
          C[(size_t)row * N + col] = v + aux[col];
        } else {
          float d = aux[row] + aux[col] - 2.0f * v;
          C[(size_t)row * N + col] = fmaxf(d, 0.0f);
        }
      }
    }
  }
}

// ---------------- unary = -log(softmax(logits)+1e-10), one wave per row ----------
__global__ __launch_bounds__(256) void unary_k(const float* __restrict__ logits,
                                               float* __restrict__ unary) {
  const int wid = threadIdx.x >> 6, lane = threadIdx.x & 63;
  const int row = blockIdx.x * 4 + wid;
  const float* lp = logits + (size_t)row * NC;
  float v[4];
#pragma unroll
  for (int j = 0; j < 4; j++) v[j] = lp[lane + 64 * j];
  float m = fmaxf(fmaxf(v[0], v[1]), fmaxf(v[2], v[3]));
#pragma unroll
  for (int o = 32; o >= 1; o >>= 1) m = fmaxf(m, __shfl_xor(m, o, 64));
  float e[4], s = 0.f;
#pragma unroll
  for (int j = 0; j < 4; j++) { e[j] = expf(v[j] - m); s += e[j]; }
#pragma unroll
  for (int o = 32; o >= 1; o >>= 1) s += __shfl_xor(s, o, 64);
  float* up = unary + (size_t)row * NC;
#pragma unroll
  for (int j = 0; j < 4; j++) up[lane + 64 * j] = -logf(e[j] / s + 1e-10f);
}

// ---- Y2 layout: class c, point k -> ((c>>5)<<17) + ((k>>3)*32 + (c&31))*8 + (k&7)

// ---------------- Y0 = softmax(-unary) -> out(f32), Y2(bf16 tiled) ----------
__global__ __launch_bounds__(256) void smax0(const float* __restrict__ unary,
                                             float* __restrict__ Yout,
                                             unsigned short* __restrict__ Yt) {
  const int tid = threadIdx.x;
  const int wid = tid >> 6, lane = tid & 63;
  const int rb = blockIdx.x;  // 16 rows per block
  __shared__ __align__(16) unsigned short yt[256][24];
  for (int rr = wid; rr < 16; rr += 4) {
    const int row = rb * 16 + rr;
    float z[4];
#pragma unroll
    for (int j = 0; j < 4; j++) z[j] = -unary[(size_t)row * NC + lane + 64 * j];
    float m = fmaxf(fmaxf(z[0], z[1]), fmaxf(z[2], z[3]));
#pragma unroll
    for (int o = 32; o >= 1; o >>= 1) m = fmaxf(m, __shfl_xor(m, o, 64));
    float e[4], s = 0.f;
#pragma unroll
    for (int j = 0; j < 4; j++) { e[j] = expf(z[j] - m); s += e[j]; }
#pragma unroll
    for (int o = 32; o >= 1; o >>= 1) s += __shfl_xor(s, o, 64);
#pragma unroll
    for (int j = 0; j < 4; j++) {
      int c = lane + 64 * j;
      float y = e[j] / s;
      Yout[(size_t)row * NC + c] = y;
      yt[c][rr] = f2b(y);
    }
  }
  __syncthreads();
  const int c = tid;
#pragma unroll
  for (int r8 = 0; r8 < 2; ++r8) {
    unsigned v[4];
#pragma unroll
    for (int k = 0; k < 4; ++k) {
      unsigned lo = yt[c][r8 * 8 + 2 * k];
      unsigned hi = yt[c][r8 * 8 + 2 * k + 1];
      v[k] = lo | (hi << 16);
    }
    size_t off = ((size_t)(c >> 5) << 17) +
                 (size_t)(((rb * 2 + r8) * 32 + (c & 31)) * 8);
    *(uint4*)&Yt[off] = make_uint4(v[0], v[1], v[2], v[3]);
  }
}

// ---------------- per-row 5th-smallest d2 -> atomicAdd(sqrt) into sig ------------
__global__ __launch_bounds__(256) void kth_k(const float* __restrict__ d2,
                                             float* __restrict__ sig) {
  const int row = blockIdx.x, tid = threadIdx.x;
  const float* rp = d2 + (size_t)row * NP;
  float b[5];
#pragma unroll
  for (int q = 0; q < 5; q++) b[q] = __int_as_float(0x7f800000);
  for (int s = 0; s < 16; s++) {
    float v = rp[tid + 256 * s];
    if (v < b[4]) {
      b[4] = v;
#pragma unroll
      for (int q = 4; q > 0; q--)
        if (b[q] < b[q - 1]) { float t = b[q]; b[q] = b[q - 1]; b[q - 1] = t; }
    }
  }
  __shared__ float ls[256 * 5];
#pragma unroll
  for (int q = 0; q < 5; q++) ls[tid * 5 + q] = b[q];
  __syncthreads();
  for (int st = 128; st >= 1; st >>= 1) {
    if (tid < st) {
      float* xs = &ls[tid * 5];
      float* ys = &ls[(tid + st) * 5];
      float r[5]; int i = 0, j = 0;
#pragma unroll
      for (int q = 0; q < 5; q++) r[q] = (xs[i] <= ys[j]) ? xs[i++] : ys[j++];
#pragma unroll
      for (int q = 0; q < 5; q++) xs[q] = r[q];
    }
    __syncthreads();
  }
  if (tid == 0) atomicAdd(sig, sqrtf(ls[4]));
}

// ---------------- Kb = bf16(exp(-d2/(2 sigma^2))) --------------------------------
__global__ __launch_bounds__(256) void expk(const float* __restrict__ d2,
                                            unsigned short* __restrict__ Kb,
                                            const float* __restrict__ sig) {
  float sigma = (*sig) * (1.0f / NP);
  float c = -1.0f / (2.0f * sigma * sigma);
  size_t i = ((size_t)blockIdx.x * 256 + threadIdx.x) * 4;
  float4 v = *(const float4*)&d2[i];
  ushort4 o;
  o.x = f2b(expf(v.x * c)); o.y = f2b(expf(v.y * c));
  o.z = f2b(expf(v.z * c)); o.w = f2b(expf(v.w * c));
  *(ushort4*)&Kb[i] = o;
}

// ---------------- persistent loop kernel v3.1 (Y prefetch depth 2) ----------------
__global__ __launch_bounds__(512) void loop_k(const unsigned short* __restrict__ Kb,
                                              unsigned short* __restrict__ Yt0,
                                              unsigned short* __restrict__ Yt1,
                                              const float* __restrict__ unary,
                                              float* __restrict__ out,
                                              double* __restrict__ Ed,
                                              unsigned* __restrict__ flags,
                                              unsigned* __restrict__ gen) {
  const int tid = threadIdx.x, lane = tid & 63, wid = tid >> 6;
  const int blk = blockIdx.x;
  const int R0 = blk * 16;
  const int l15 = lane & 15, l16 = lane >> 4;
  constexpr int LDA = 520;  // bf16 elems (512 + 8 pad)
  constexpr int LDP = 260;  // f32 (1040B row: 16B-aligned)
  constexpr int LDY = 258;
  __shared__ __align__(16) unsigned short sA[2][16 * LDA];  // 2 x 16.6 KB
  __shared__ __align__(16) float P[16 * LDP];               // 16.6 KB
  __shared__ __align__(16) unsigned short yt[16 * LDY];     // 8.3 KB
  __shared__ double ered[8];
  float oldEf = __int_as_float(0x7f800000);

  const int b0 = l15 * 8;          // Y2 elem offset, n=0
  const int b1 = (16 + l15) * 8;   // n=1
  const int sr0 = tid >> 6, sc0 = tid & 63;
  const int sr1 = (512 + tid) >> 6, sc1 = tid & 63;

  for (int iter = 0; iter < MAXIT; ++iter) {
    const unsigned short* Yrd = ((iter & 1) ? Yt1 : Yt0) + ((size_t)wid << 17);
    unsigned short* Ywr = (iter & 1) ? Yt0 : Yt1;

    f32x4 acc[2];
    acc[0] = 0.0f; acc[1] = 0.0f;

    // prologue: prefetch Kb chunk 0 + Y subs 0,1 (depth-2 pipeline)
    uint4 pre0 = *(const uint4*)&Kb[(size_t)(R0 + sr0) * NP + sc0 * 8];
    uint4 pre1 = *(const uint4*)&Kb[(size_t)(R0 + sr1) * NP + sc1 * 8];
    bf16x8 qa[2][2], qb[2][2], cb[2][2];
    // frags for global k8 base kq: [n][kk] at (kq + kk*4 + l16)*256 + b{n}
    qa[0][0] = *(const bf16x8*)&Yrd[(size_t)(0 + l16) * 256 + b0];
    qa[0][1] = *(const bf16x8*)&Yrd[(size_t)(4 + l16) * 256 + b0];
    qa[1][0] = *(const bf16x8*)&Yrd[(size_t)(0 + l16) * 256 + b1];
    qa[1][1] = *(const bf16x8*)&Yrd[(size_t)(4 + l16) * 256 + b1];
    qb[0][0] = *(const bf16x8*)&Yrd[(size_t)(8 + l16) * 256 + b0];
    qb[0][1] = *(const bf16x8*)&Yrd[(size_t)(12 + l16) * 256 + b0];
    qb[1][0] = *(const bf16x8*)&Yrd[(size_t)(8 + l16) * 256 + b1];
    qb[1][1] = *(const bf16x8*)&Yrd[(size_t)(12 + l16) * 256 + b1];

    for (int ch = 0; ch < 8; ++ch) {
      unsigned short* buf = sA[ch & 1];
      *(uint4*)&buf[sr0 * LDA + sc0 * 8] = pre0;
      *(uint4*)&buf[sr1 * LDA + sc1 * 8] = pre1;
      __syncthreads();
      if (ch < 7) {
        pre0 = *(const uint4*)&Kb[(size_t)(R0 + sr0) * NP + (ch + 1) * 512 + sc0 * 8];
        pre1 = *(const uint4*)&Kb[(size_t)(R0 + sr1) * NP + (ch + 1) * 512 + sc1 * 8];
      }
#pragma unroll
      for (int sub = 0; sub < 8; ++sub) {
        // rotate pipeline: cb <- qa <- qb <- load(cur+16)
#pragma unroll
        for (int n = 0; n < 2; ++n)
#pragma unroll
          for (int kk = 0; kk < 2; ++kk) { cb[n][kk] = qa[n][kk]; qa[n][kk] = qb[n][kk]; }
        {
          int kq = ch * 64 + sub * 8 + 16;
          if (kq > 504) kq = 504;  // clamp: harmless dup load at tail
          qb[0][0] = *(const bf16x8*)&Yrd[(size_t)(kq + l16) * 256 + b0];
          qb[0][1] = *(const bf16x8*)&Yrd[(size_t)(kq + 4 + l16) * 256 + b0];
          qb[1][0] = *(const bf16x8*)&Yrd[(size_t)(kq + l16) * 256 + b1];
          qb[1][1] = *(const bf16x8*)&Yrd[(size_t)(kq + 4 + l16) * 256 + b1];
        }
        bf16x8 af[2];
        af[0] = *(const bf16x8*)&buf[l15 * LDA + sub * 64 + l16 * 8];
        af[1] = *(const bf16x8*)&buf[l15 * LDA + sub * 64 + 32 + l16 * 8];
#pragma unroll
        for (int kk = 0; kk < 2; ++kk)
#pragma unroll
          for (int n = 0; n < 2; ++n)
            acc[n] = __builtin_amdgcn_mfma_f32_16x16x32_bf16(af[kk], cb[n][kk], acc[n], 0, 0, 0);
      }
      __syncthreads();
    }
    // acc -> P: row = l16*4+j, col = wid*32 + n*16 + l15
#pragma unroll
    for (int n = 0; n < 2; ++n)
#pragma unroll
      for (int j = 0; j < 4; ++j)
        P[(l16 * 4 + j) * LDP + wid * 32 + n * 16 + l15] = acc[n][j];
    __syncthreads();

    // softmax: wave w handles rows wid*2 .. +1
    double ep = 0.0;
#pragma unroll
    for (int h = 0; h < 2; ++h) {
      const int r = wid * 2 + h;
      const int row = R0 + r;
      const int c0 = lane * 4;
      float4 p4 = *(const float4*)&P[r * LDP + c0];
      float pv[4] = {p4.x, p4.y, p4.z, p4.w};
      float4 u4 = *(const float4*)&unary[(size_t)row * NC + c0];
      float uu[4] = {u4.x, u4.y, u4.z, u4.w};
      float z[4];
#pragma unroll
      for (int q = 0; q < 4; ++q) z[q] = pv[q] - uu[q];
      float m = fmaxf(fmaxf(z[0], z[1]), fmaxf(z[2], z[3]));
#pragma unroll
      for (int o = 32; o >= 1; o >>= 1) m = fmaxf(m, __shfl_xor(m, o, 64));
      float e[4], ssum = 0.f;
#pragma unroll
      for (int q = 0; q < 4; ++q) { e[q] = expf(z[q] - m); ssum += e[q]; }
#pragma unroll
      for (int o = 32; o >= 1; o >>= 1) ssum += __shfl_xor(ssum, o, 64);
      float inv = 1.0f / ssum;
      float y[4];
#pragma unroll
      for (int q = 0; q < 4; ++q) {
        y[q] = e[q] * inv;
        ep += (double)(y[q] * (uu[q] - pv[q] + logf(fmaxf(y[q], 1e-20f))));
        yt[r * LDY + c0 + q] = f2b(y[q]);
      }
      float4 o4; o4.x = y[0]; o4.y = y[1]; o4.z = y[2]; o4.w = y[3];
      *(float4*)&out[(size_t)row * NC + c0] = o4;
    }
#pragma unroll
    for (int o = 32; o >= 1; o >>= 1) ep += __shfl_xor(ep, o, 64);
    if (lane == 0) ered[wid] = ep;
    __syncthreads();

    // flush Y2: thread (c = tid&255, r8 = tid>>8) packs 8 rows of class c
    {
      const int c = tid & 255, r8 = tid >> 8;
      unsigned v[4];
#pragma unroll
      for (int k = 0; k < 4; ++k) {
        unsigned lo = yt[(r8 * 8 + 2 * k) * LDY + c];
        unsigned hi = yt[(r8 * 8 + 2 * k + 1) * LDY + c];
        v[k] = lo | (hi << 16);
      }
      size_t off = ((size_t)(c >> 5) << 17) +
                   (size_t)(((blk * 2 + r8) * 32 + (c & 31)) * 8);
      *(uint4*)&Ywr[off] = make_uint4(v[0], v[1], v[2], v[3]);
    }
    if (tid == 0) {
      double eblk = 0.0;
#pragma unroll
      for (int w = 0; w < 8; ++w) eblk += ered[w];
      atomicAdd(&Ed[iter], eblk);
    }
    gridbar(flags, gen, (unsigned)(iter + 1), tid, NBLK2);

    double Ec = __hip_atomic_load(&Ed[iter], __ATOMIC_RELAXED, __HIP_MEMORY_SCOPE_AGENT);
    float Ef = (float)Ec;
    if (iter > 1 && fabsf(Ef - oldEf) <= 1e-8f * fabsf(oldEf)) break;  // frozen
    oldEf = Ef;
  }
}

extern "C" void kernel_launch(void* const* d_in, const int* in_sizes, int n_in,
                              void* d_out, int out_size, void* d_ws, size_t ws_size,
                              hipStream_t stream) {
  const float* x = (const float*)d_in[0];
  const float* W = (const float*)d_in[1];
  const float* bias = (const float*)d_in[2];
  float* out = (float*)d_out;

  char* p = (char*)d_ws;
  auto take = [&](size_t bytes) {
    char* r = p;
    p += (bytes + 255) & ~(size_t)255;
    return r;
  };
  float* d2          = (float*)take((size_t)NP * NP * 4);          // 64 MB
  unsigned short* Kb = (unsigned short*)take((size_t)NP * NP * 2); // 32 MB
  unsigned short* F  = (unsigned short*)take((size_t)NP * DIMF * 2);
  unsigned short* xb = (unsigned short*)take((size_t)NP * DIMF * 2);
  unsigned short* Wb = (unsigned short*)take((size_t)NC * DIMF * 2);
  unsigned short* Yt0 = (unsigned short*)take((size_t)NC * NP * 2);
  unsigned short* Yt1 = (unsigned short*)take((size_t)NC * NP * 2);
  float* logits = (float*)take((size_t)NP * NC * 4);
  float* unary  = (float*)take((size_t)NP * NC * 4);
  float* sqF    = (float*)take((size_t)NP * 4);
  float* sig    = (float*)take(256);
  double* Ed    = (double*)take(MAXIT * 8);
  unsigned* flags = (unsigned*)take((size_t)NBLK2 * 32 * 4);
  unsigned* gen   = (unsigned*)take(256);

  initk<<<1, 256, 0, stream>>>(Ed, sig, flags, gen);
  castk<<<512, 256, 0, stream>>>(W, Wb);
  rownorm<<<NP, 256, 0, stream>>>(x, F, xb, sqF);
  // logits = x @ W^T + b   (m97-style gload_lds GEMM)
  gemm2<64, 64, 0><<<dim3(64, 4), 256, 0, stream>>>(xb, Wb, logits, NP, NC, DIMF, bias);
  unary_k<<<1024, 256, 0, stream>>>(logits, unary);
  smax0<<<256, 256, 0, stream>>>(unary, out, Yt0);
  // d2 = max(sq_i + sq_j - 2 F F^T, 0)   (m97-style gload_lds GEMM)
  gemm2<128, 128, 1><<<dim3(32, 32), 256, 0, stream>>>(F, F, d2, NP, NP, DIMF, sqF);
  kth_k<<<NP, 256, 0, stream>>>(d2, sig);
  expk<<<16384, 256, 0, stream>>>(d2, Kb, sig);
  // laplacian loop: persistent kernel, homemade grid barrier (256 co-resident blocks)
  loop_k<<<NBLK2, 512, 0, stream>>>(Kb, Yt0, Yt1, unary, out, Ed, flags, gen);
}